// Round 4
// baseline (24.998 us; speedup 1.0000x reference)
//
#include <hip/hip_runtime.h>

// Problem constants (from reference): B=32, S=1024, D=768, W=512
#define BB 32
#define SS 1024
#define DD 768
#define WW 512

// Native clang vector type — required by __builtin_nontemporal_*.
typedef float f4 __attribute__((ext_vector_type(4)));

// One 64-lane wave per word; each lane handles 3 float4 (64*3*4 = 768 floats).
// 256-thread blocks -> 4 words per block, grid = B*W/4 = 4096 blocks.
// Output stores are non-temporal: pure streaming write, never re-read ->
// don't let them allocate in L2/L3 and evict the embedding stream.
__global__ __launch_bounds__(256) void word_mean_kernel(
    const float* __restrict__ emb,     // [B, S, D] float32
    const int*   __restrict__ offsets, // [B, W, 2] int32 (JAX x64 disabled -> int32)
    const int*   __restrict__ mask,    // [B, W]    int32
    float*       __restrict__ out)     // [B, W, D] float32
{
    const int wave = threadIdx.x >> 6;              // 0..3
    const int lane = threadIdx.x & 63;
    const int word = (blockIdx.x << 2) + wave;      // 0..B*W-1
    const int b    = word >> 9;                     // word / W

    const int st  = offsets[word * 2 + 0];
    const int ed  = offsets[word * 2 + 1];
    const int m   = mask[word];
    const int len = ed - st;

    f4 r0 = (f4)(0.f);
    f4 r1 = r0, r2 = r0;

    if (m != 0 && len > 0) {
        const f4* p0 = (const f4*)(emb + ((size_t)b * SS + st) * DD);
        r0 = p0[lane];
        r1 = p0[lane + 64];
        r2 = p0[lane + 128];
        if (len == 2) {
            const f4* p1 = p0 + (DD / 4);
            r0 += p1[lane];
            r1 += p1[lane + 64];
            r2 += p1[lane + 128];
            r0 *= 0.5f;
            r1 *= 0.5f;
            r2 *= 0.5f;
        }
    }

    f4* o = (f4*)(out + (size_t)word * DD);
    __builtin_nontemporal_store(r0, &o[lane]);
    __builtin_nontemporal_store(r1, &o[lane + 64]);
    __builtin_nontemporal_store(r2, &o[lane + 128]);
}

extern "C" void kernel_launch(void* const* d_in, const int* in_sizes, int n_in,
                              void* d_out, int out_size, void* d_ws, size_t ws_size,
                              hipStream_t stream) {
    const float* emb     = (const float*)d_in[0];
    const int*   offsets = (const int*)d_in[1];
    const int*   mask    = (const int*)d_in[2];
    float*       out     = (float*)d_out;

    dim3 grid((BB * WW) / 4);  // 4096 blocks
    dim3 block(256);           // 4 waves = 4 words per block
    hipLaunchKernelGGL(word_mean_kernel, grid, block, 0, stream,
                       emb, offsets, mask, out);
}

// Round 5
// 23.930 us; speedup vs baseline: 1.0446x; 1.0446x over previous
//
#include <hip/hip_runtime.h>

// Problem constants (from reference): B=32, S=1024, D=768, W=512
#define BB 32
#define SS 1024
#define DD 768
#define WW 512

typedef float f4 __attribute__((ext_vector_type(4)));

// 2 words per 64-lane wave, 4 waves/block -> 8 words/block, grid = 2048.
// Row-0 loads for both words are unconditional (clamped addr, zeroed later)
// so 6 independent dwordx4 loads issue before any waitcnt -> high MLP.
// Second-row (len==2) loads stay behind wave-uniform branches to keep
// read traffic minimal. Plain stores (NT regressed in round 4).
__global__ __launch_bounds__(256) void word_mean_kernel(
    const float* __restrict__ emb,     // [B, S, D] float32
    const int*   __restrict__ offsets, // [B, W, 2] int32
    const int*   __restrict__ mask,    // [B, W]    int32
    float*       __restrict__ out)     // [B, W, D] float32
{
    const int wave = threadIdx.x >> 6;
    const int lane = threadIdx.x & 63;
    const int w0   = (blockIdx.x << 3) + (wave << 1);  // first word of pair
    const int w1   = w0 + 1;
    const int bA   = w0 >> 9;   // batch index (w1 may cross into next batch)
    const int bB   = w1 >> 9;

    const int stA = offsets[w0 * 2 + 0];
    const int edA = offsets[w0 * 2 + 1];
    const int mA  = mask[w0];
    const int stB = offsets[w1 * 2 + 0];
    const int edB = offsets[w1 * 2 + 1];
    const int mB  = mask[w1];

    const int lenA = edA - stA;
    const int lenB = edB - stB;
    const bool vA = (mA != 0) && (lenA > 0);
    const bool vB = (mB != 0) && (lenB > 0);

    // Clamped row index: always a legal address even for invalid words.
    const int rA = vA ? stA : 0;
    const int rB = vB ? stB : 0;

    const f4* pA = (const f4*)(emb + ((size_t)bA * SS + rA) * DD);
    const f4* pB = (const f4*)(emb + ((size_t)bB * SS + rB) * DD);

    // 6 independent unconditional loads — issue before any use.
    f4 a0 = pA[lane];
    f4 a1 = pA[lane + 64];
    f4 a2 = pA[lane + 128];
    f4 b0 = pB[lane];
    f4 b1 = pB[lane + 64];
    f4 b2 = pB[lane + 128];

    if (vA && lenA == 2) {           // wave-uniform
        a0 += pA[lane + 192];        // row st+1 (DD/4 = 192 f4 per row)
        a1 += pA[lane + 256];
        a2 += pA[lane + 320];
        a0 *= 0.5f; a1 *= 0.5f; a2 *= 0.5f;
    }
    if (vB && lenB == 2) {           // wave-uniform
        b0 += pB[lane + 192];
        b1 += pB[lane + 256];
        b2 += pB[lane + 320];
        b0 *= 0.5f; b1 *= 0.5f; b2 *= 0.5f;
    }
    if (!vA) { a0 = (f4)(0.f); a1 = (f4)(0.f); a2 = (f4)(0.f); }
    if (!vB) { b0 = (f4)(0.f); b1 = (f4)(0.f); b2 = (f4)(0.f); }

    f4* oA = (f4*)(out + (size_t)w0 * DD);
    f4* oB = (f4*)(out + (size_t)w1 * DD);
    oA[lane]       = a0;
    oA[lane + 64]  = a1;
    oA[lane + 128] = a2;
    oB[lane]       = b0;
    oB[lane + 64]  = b1;
    oB[lane + 128] = b2;
}

extern "C" void kernel_launch(void* const* d_in, const int* in_sizes, int n_in,
                              void* d_out, int out_size, void* d_ws, size_t ws_size,
                              hipStream_t stream) {
    const float* emb     = (const float*)d_in[0];
    const int*   offsets = (const int*)d_in[1];
    const int*   mask    = (const int*)d_in[2];
    float*       out     = (float*)d_out;

    dim3 grid((BB * WW) / 8);  // 2048 blocks
    dim3 block(256);           // 4 waves, 2 words each
    hipLaunchKernelGGL(word_mean_kernel, grid, block, 0, stream,
                       emb, offsets, mask, out);
}